// Round 1
// baseline (600.143 us; speedup 1.0000x reference)
//
#include <hip/hip_runtime.h>

#define N_USERS 100000
#define N_ITEMS 50000
#define N_TOTAL 150000
#define DIM 64
#define NNZ_C 4800000
#define NELEM (N_TOTAL * DIM)        // 9,600,000 elements
#define NELEM4 (NELEM / 4)           // 2,400,000 x4-vectors

#define RPB 74                       // rows per bucket
#define NB 2048                      // buckets (2048*74 >= 150000)
#define NBLK 512                     // scatter blocks
#define CHUNK (NNZ_C / NBLK)         // 9375 nnz per scatter block (exact)
#define CAP 4096                     // max entries/bucket staged (mean 2344)
#define CPAD 16                      // pad T/cursor counters to 1 per 64B line

typedef unsigned short ush;

__device__ __forceinline__ float bf2f(ush u) {
    return __uint_as_float(((unsigned)u) << 16);
}
__device__ __forceinline__ ush f2bf(float f) {   // round-to-nearest-even
    unsigned u = __float_as_uint(f);
    return (ush)((u + 0x7fffu + ((u >> 16) & 1u)) >> 16);
}

// init: A(bf16) = concat(user,item) = e0 (out is written only by the fused
// final layer).
__global__ __launch_bounds__(256) void init_kernel(
    const float4* __restrict__ user, const float4* __restrict__ item,
    ushort4* __restrict__ A16) {
    int i = blockIdx.x * 256 + threadIdx.x;
    if (i >= NELEM4) return;
    const int u4 = N_USERS * DIM / 4;
    float4 v = (i < u4) ? user[i] : item[i - u4];
    ushort4 b;
    b.x = f2bf(v.x); b.y = f2bf(v.y); b.z = f2bf(v.z); b.w = f2bf(v.w);
    A16[i] = b;
}

// P1: per-block bucket histogram in LDS -> histmat[block][bucket],
// plus global bucket totals T (padded counters; T zeroed by memset).
__global__ __launch_bounds__(1024) void p1_hist(
    const int* __restrict__ row, int* __restrict__ histmat,
    int* __restrict__ T) {
    __shared__ int h[NB];
    int t = threadIdx.x, b = blockIdx.x;
    for (int j = t; j < NB; j += 1024) h[j] = 0;
    __syncthreads();
    int kbeg = b * CHUNK, kend = kbeg + CHUNK;
    for (int k = kbeg + t; k < kend; k += 1024) {
        unsigned r = (unsigned)row[k];
        atomicAdd(&h[r / RPB], 1);
    }
    __syncthreads();
    for (int j = t; j < NB; j += 1024) {
        int c = h[j];
        histmat[b * NB + j] = c;
        if (c) atomicAdd(&T[j * CPAD], c);
    }
}

// P2b: single block exclusive scan of T[2048] -> bucketbase[0..2048];
// also initializes the atomic claim cursors (padded) to bucketbase.
__global__ __launch_bounds__(1024) void p2b_scan(
    const int* __restrict__ T, int* __restrict__ bucketbase,
    int* __restrict__ cursor, int* __restrict__ rowptr) {
    __shared__ int s[1024];
    int t = threadIdx.x;
    int v0 = T[(2 * t) * CPAD], v1 = T[(2 * t + 1) * CPAD];
    int pair = v0 + v1;
    s[t] = pair;
    __syncthreads();
    for (int off = 1; off < 1024; off <<= 1) {
        int w = (t >= off) ? s[t - off] : 0;
        __syncthreads();
        s[t] += w;
        __syncthreads();
    }
    int excl = s[t] - pair;
    bucketbase[2 * t] = excl;
    bucketbase[2 * t + 1] = excl + v0;
    cursor[(2 * t) * CPAD] = excl;
    cursor[(2 * t + 1) * CPAD] = excl + v0;
    if (t == 1023) { bucketbase[NB] = s[t]; rowptr[N_TOTAL] = NNZ_C; }
}

// P3: bucket-sort the chunk in LDS, then write runs of consecutive global
// slots (~4.6 entries per (block,bucket) segment). Global segment bases are
// CLAIMED via atomicAdd on padded per-bucket cursors (replaces the old
// p2a column-scan + basemat; within-bucket segment order becomes
// nondeterministic, which only permutes the fp add order — already
// nondeterministic via the LDS atomics). LDS ~133KB -> 1 block/CU.
__global__ __launch_bounds__(1024) void p3_scatter(
    const int* __restrict__ row, const int* __restrict__ col,
    const float* __restrict__ vals, const int* __restrict__ histmat,
    int* __restrict__ cursor, uint2* __restrict__ entries) {
    __shared__ int s[1024];
    __shared__ int wp[NB];       // running LDS write position per bucket
    __shared__ int gbase[NB];    // global dest = gbase[j] + local pos
    __shared__ uint2 sorted[CHUNK];
    __shared__ int dest[CHUNK];
    int t = threadIdx.x, b = blockIdx.x;

    // local exclusive scan of this block's 2048 bucket counts (2/thread)
    int c0 = histmat[b * NB + 2 * t];
    int c1 = histmat[b * NB + 2 * t + 1];
    int pair = c0 + c1;
    s[t] = pair;
    __syncthreads();
    for (int off = 1; off < 1024; off <<= 1) {
        int w = (t >= off) ? s[t - off] : 0;
        __syncthreads();
        s[t] += w;
        __syncthreads();
    }
    int excl = s[t] - pair;              // lofs of bucket 2t
    wp[2 * t] = excl;
    wp[2 * t + 1] = excl + c0;
    // claim this block's segment in each bucket's global region
    int g0 = c0 ? atomicAdd(&cursor[(2 * t) * CPAD], c0) : 0;
    int g1 = c1 ? atomicAdd(&cursor[(2 * t + 1) * CPAD], c1) : 0;
    gbase[2 * t]     = g0 - excl;
    gbase[2 * t + 1] = g1 - (excl + c0);
    __syncthreads();

    int kbeg = b * CHUNK, kend = kbeg + CHUNK;
    for (int k = kbeg + t; k < kend; k += 1024) {
        unsigned r = (unsigned)row[k];
        unsigned j = r / RPB;
        unsigned rl = r - j * RPB;
        int pos = atomicAdd(&wp[j], 1);
        sorted[pos] = make_uint2((rl << 18) | (unsigned)col[k],
                                 __float_as_uint(vals[k]));
        dest[pos] = gbase[j] + pos;
    }
    __syncthreads();
    for (int i = t; i < CHUNK; i += 1024)
        entries[dest[i]] = sorted[i];
}

// P4: one block per bucket; stage in LDS, counting-sort by 74 local rows,
// rewrite region in place as fine CSR int2{col,val}; emit rowptr.
__global__ __launch_bounds__(512) void p4_sort(
    const int* __restrict__ bucketbase, uint2* __restrict__ entries,
    int* __restrict__ rowptr) {
    __shared__ uint2 stage[CAP];
    __shared__ int cnt[128], scanb[128], wp[128];
    int t = threadIdx.x, b = blockIdx.x;
    int base = bucketbase[b];
    int n = bucketbase[b + 1] - base;
    if (n > CAP) n = CAP;   // statistically impossible; avoids LDS overrun
    if (t < 128) cnt[t] = 0;
    __syncthreads();
    for (int i = t; i < n; i += 512) {
        uint2 e = entries[base + i];
        stage[i] = e;
        atomicAdd(&cnt[e.x >> 18], 1);
    }
    __syncthreads();
    if (t < 128) scanb[t] = cnt[t];
    __syncthreads();
    for (int off = 1; off < 128; off <<= 1) {
        int w = 0;
        if (t < 128 && t >= off) w = scanb[t - off];
        __syncthreads();
        if (t < 128) scanb[t] += w;
        __syncthreads();
    }
    if (t < RPB) {
        int excl = scanb[t] - cnt[t];
        wp[t] = excl;
        int rg = b * RPB + t;
        if (rg < N_TOTAL) rowptr[rg] = base + excl;
    }
    __syncthreads();
    for (int i = t; i < n; i += 512) {
        uint2 e = stage[i];
        unsigned rl = e.x >> 18;
        int pos = atomicAdd(&wp[rl], 1);
        ((int2*)entries)[base + pos] =
            make_int2((int)(e.x & 0x3FFFFu), (int)e.y);
    }
}

// 4 rows/wave, 16 lanes/row, bf16 gathers. y = S * x (bf16 out).
__global__ __launch_bounds__(256) void spmm_csr_kernel(
    const int* __restrict__ rowptr, const int2* __restrict__ csr,
    const ushort4* __restrict__ x4, ushort4* __restrict__ y4) {
    int gid = blockIdx.x * 256 + threadIdx.x;
    int lane = threadIdx.x & 63;
    int group = lane >> 4;
    int chunk = lane & 15;
    int r = (gid >> 6) * 4 + group;
    if (r >= N_TOTAL) return;
    int start = rowptr[r], end = rowptr[r + 1];
    float4 acc = make_float4(0.f, 0.f, 0.f, 0.f);
    for (int j0 = start; j0 < end; j0 += 16) {
        int j = j0 + chunk;
        int2 pair = make_int2(0, 0);
        if (j < end) pair = csr[j];
        int cnt = min(16, end - j0);
        #pragma unroll 4
        for (int t = 0; t < cnt; t++) {
            int src = group * 16 + t;
            int cc = __shfl(pair.x, src);
            float vv = __int_as_float(__shfl(pair.y, src));
            ushort4 xv = x4[cc * 16 + chunk];
            acc.x += vv * bf2f(xv.x);
            acc.y += vv * bf2f(xv.y);
            acc.z += vv * bf2f(xv.z);
            acc.w += vv * bf2f(xv.w);
        }
    }
    int o = r * 16 + chunk;
    ushort4 yb;
    yb.x = f2bf(acc.x); yb.y = f2bf(acc.y);
    yb.z = f2bf(acc.z); yb.w = f2bf(acc.w);
    y4[o] = yb;
}

// final layer fused with merge: acc = S*e2 (fp32 regs);
// out = (e0 + e1 + e2 + acc) * 0.25
__global__ __launch_bounds__(256) void spmm_merge_kernel(
    const int* __restrict__ rowptr, const int2* __restrict__ csr,
    const ushort4* __restrict__ x4 /*e2*/, const ushort4* __restrict__ e0,
    const ushort4* __restrict__ e1, float4* __restrict__ out) {
    int gid = blockIdx.x * 256 + threadIdx.x;
    int lane = threadIdx.x & 63;
    int group = lane >> 4;
    int chunk = lane & 15;
    int r = (gid >> 6) * 4 + group;
    if (r >= N_TOTAL) return;
    int start = rowptr[r], end = rowptr[r + 1];
    float4 acc = make_float4(0.f, 0.f, 0.f, 0.f);
    for (int j0 = start; j0 < end; j0 += 16) {
        int j = j0 + chunk;
        int2 pair = make_int2(0, 0);
        if (j < end) pair = csr[j];
        int cnt = min(16, end - j0);
        #pragma unroll 4
        for (int t = 0; t < cnt; t++) {
            int src = group * 16 + t;
            int cc = __shfl(pair.x, src);
            float vv = __int_as_float(__shfl(pair.y, src));
            ushort4 xv = x4[cc * 16 + chunk];
            acc.x += vv * bf2f(xv.x);
            acc.y += vv * bf2f(xv.y);
            acc.z += vv * bf2f(xv.z);
            acc.w += vv * bf2f(xv.w);
        }
    }
    int o = r * 16 + chunk;
    ushort4 a = e0[o], b = e1[o], c = x4[o];
    float4 oo;
    oo.x = (bf2f(a.x) + bf2f(b.x) + bf2f(c.x) + acc.x) * 0.25f;
    oo.y = (bf2f(a.y) + bf2f(b.y) + bf2f(c.y) + acc.y) * 0.25f;
    oo.z = (bf2f(a.z) + bf2f(b.z) + bf2f(c.z) + acc.z) * 0.25f;
    oo.w = (bf2f(a.w) + bf2f(b.w) + bf2f(c.w) + acc.w) * 0.25f;
    out[o] = oo;
}

extern "C" void kernel_launch(void* const* d_in, const int* in_sizes, int n_in,
                              void* d_out, int out_size, void* d_ws, size_t ws_size,
                              hipStream_t stream) {
    const float* user_emb = (const float*)d_in[0];
    const float* item_emb = (const float*)d_in[1];
    const int*   adj_row  = (const int*)d_in[2];
    const int*   adj_col  = (const int*)d_in[3];
    const float* adj_vals = (const float*)d_in[4];
    float* out = (float*)d_out;

    ush*   A          = (ush*)d_ws;                 // 19.2 MB (e0)
    ush*   B          = A + NELEM;                  // 19.2 MB (e1)
    ush*   C          = B + NELEM;                  // 19.2 MB (e2)
    uint2* entries    = (uint2*)(C + NELEM);        // 38.4 MB (becomes fine CSR)
    int*   histmat    = (int*)(entries + NNZ_C);    // 512*2048 = 4 MB
    int*   T          = histmat + NBLK * NB;        // 2048 padded counters, 128 KB
    int*   cursor     = T + NB * CPAD;              // 2048 padded cursors, 128 KB
    int*   bucketbase = cursor + NB * CPAD;         // 2049
    int*   rowptr     = bucketbase + NB + 1;        // 150001

    const int eltBlocks  = (NELEM4 + 255) / 256;
    const int spmmBlocks = N_TOTAL / 16;            // 9375 (exact)

    hipMemsetAsync(T, 0, NB * CPAD * sizeof(int), stream);

    init_kernel<<<eltBlocks, 256, 0, stream>>>(
        (const float4*)user_emb, (const float4*)item_emb, (ushort4*)A);
    p1_hist<<<NBLK, 1024, 0, stream>>>(adj_row, histmat, T);
    p2b_scan<<<1, 1024, 0, stream>>>(T, bucketbase, cursor, rowptr);
    p3_scatter<<<NBLK, 1024, 0, stream>>>(adj_row, adj_col, adj_vals,
                                          histmat, cursor, entries);
    p4_sort<<<NB, 512, 0, stream>>>(bucketbase, entries, rowptr);

    spmm_csr_kernel<<<spmmBlocks, 256, 0, stream>>>(rowptr, (const int2*)entries,
        (const ushort4*)A, (ushort4*)B);    // e1 = S e0
    spmm_csr_kernel<<<spmmBlocks, 256, 0, stream>>>(rowptr, (const int2*)entries,
        (const ushort4*)B, (ushort4*)C);    // e2 = S e1
    spmm_merge_kernel<<<spmmBlocks, 256, 0, stream>>>(rowptr, (const int2*)entries,
        (const ushort4*)C, (const ushort4*)A, (const ushort4*)B, (float4*)out);
}

// Round 2
// 516.235 us; speedup vs baseline: 1.1625x; 1.1625x over previous
//
#include <hip/hip_runtime.h>

#define N_USERS 100000
#define N_ITEMS 50000
#define N_TOTAL 150000
#define DIM 64
#define NNZ_C 4800000
#define NELEM (N_TOTAL * DIM)        // 9,600,000 elements
#define NELEM4 (NELEM / 4)           // 2,400,000 x4-vectors

#define RPB 74                       // rows per bucket
#define NB 2048                      // buckets (2048*74 >= 150000)
#define NBLK 512                     // scatter blocks
#define CHUNK (NNZ_C / NBLK)         // 9375 nnz per scatter block (exact)
#define CAP 4096                     // max entries/bucket staged (mean 2344)
#define TILES 32                     // column-scan tiles over the block dim
#define TB (NBLK / TILES)            // 16 blocks per tile

typedef unsigned short ush;

__device__ __forceinline__ float bf2f(ush u) {
    return __uint_as_float(((unsigned)u) << 16);
}
__device__ __forceinline__ ush f2bf(float f) {   // round-to-nearest-even
    unsigned u = __float_as_uint(f);
    return (ush)((u + 0x7fffu + ((u >> 16) & 1u)) >> 16);
}

// init: A(bf16) = concat(user,item) = e0 (out is written only by the fused
// final layer).
__global__ __launch_bounds__(256) void init_kernel(
    const float4* __restrict__ user, const float4* __restrict__ item,
    ushort4* __restrict__ A16) {
    int i = blockIdx.x * 256 + threadIdx.x;
    if (i >= NELEM4) return;
    const int u4 = N_USERS * DIM / 4;
    float4 v = (i < u4) ? user[i] : item[i - u4];
    ushort4 b;
    b.x = f2bf(v.x); b.y = f2bf(v.y); b.z = f2bf(v.z); b.w = f2bf(v.w);
    A16[i] = b;
}

// P1: per-block bucket histogram in LDS -> histmat[block][bucket]
__global__ __launch_bounds__(1024) void p1_hist(
    const int* __restrict__ row, int* __restrict__ histmat) {
    __shared__ int h[NB];
    int t = threadIdx.x, b = blockIdx.x;
    for (int j = t; j < NB; j += 1024) h[j] = 0;
    __syncthreads();
    int kbeg = b * CHUNK, kend = kbeg + CHUNK;
    for (int k = kbeg + t; k < kend; k += 1024) {
        unsigned r = (unsigned)row[k];
        atomicAdd(&h[r / RPB], 1);
    }
    __syncthreads();
    for (int j = t; j < NB; j += 1024) histmat[b * NB + j] = h[j];
}

// P2a (tiled, 3 passes — replaces the 8-block serial column scan whose
// ~64KB in-flight limited it to ~100 GB/s):
// p2a1: tilesum[tile][j] = sum of 16 consecutive blocks' counts (coalesced)
__global__ __launch_bounds__(256) void p2a1_tilesum(
    const int* __restrict__ histmat, int* __restrict__ tilesum) {
    int j = blockIdx.x * 256 + threadIdx.x;   // 0..NB-1
    int tile = blockIdx.y;                    // 0..TILES-1
    int b0 = tile * TB;
    int s = 0;
    #pragma unroll
    for (int i = 0; i < TB; i++) s += histmat[(b0 + i) * NB + j];
    tilesum[tile * NB + j] = s;
}

// p2a2: per-column scan over the 32 tile sums -> tilebase, bucket totals T
__global__ __launch_bounds__(256) void p2a2_tilescan(
    const int* __restrict__ tilesum, int* __restrict__ tilebase,
    int* __restrict__ T) {
    int j = blockIdx.x * 256 + threadIdx.x;   // 0..NB-1
    int run = 0;
    #pragma unroll
    for (int t = 0; t < TILES; t++) {
        tilebase[t * NB + j] = run;
        run += tilesum[t * NB + j];
    }
    T[j] = run;
}

// p2a3: expand within each tile -> basemat[b][j] = sum_{b'<b} hist (coalesced)
__global__ __launch_bounds__(256) void p2a3_expand(
    const int* __restrict__ histmat, const int* __restrict__ tilebase,
    int* __restrict__ basemat) {
    int j = blockIdx.x * 256 + threadIdx.x;   // 0..NB-1
    int tile = blockIdx.y;                    // 0..TILES-1
    int b0 = tile * TB;
    int run = tilebase[tile * NB + j];
    #pragma unroll
    for (int i = 0; i < TB; i++) {
        basemat[(b0 + i) * NB + j] = run;
        run += histmat[(b0 + i) * NB + j];
    }
}

// P2b: single block exclusive scan of T[2048] -> bucketbase[0..2048]
__global__ __launch_bounds__(1024) void p2b_scan(
    const int* __restrict__ T, int* __restrict__ bucketbase,
    int* __restrict__ rowptr) {
    __shared__ int s[1024];
    int t = threadIdx.x;
    int v0 = T[2 * t], v1 = T[2 * t + 1];
    int pair = v0 + v1;
    s[t] = pair;
    __syncthreads();
    for (int off = 1; off < 1024; off <<= 1) {
        int w = (t >= off) ? s[t - off] : 0;
        __syncthreads();
        s[t] += w;
        __syncthreads();
    }
    int excl = s[t] - pair;
    bucketbase[2 * t] = excl;
    bucketbase[2 * t + 1] = excl + v0;
    if (t == 1023) { bucketbase[NB] = s[t]; rowptr[N_TOTAL] = NNZ_C; }
}

// P3: bucket-sort the chunk in LDS, then write runs of consecutive global
// slots (~4.6 entries per (block,bucket) segment) — ~3x fewer write-line
// touches than per-entry scatter. Uses histmat (from P1) instead of
// recounting. LDS ~133KB -> 1 block/CU.
__global__ __launch_bounds__(1024) void p3_scatter(
    const int* __restrict__ row, const int* __restrict__ col,
    const float* __restrict__ vals, const int* __restrict__ histmat,
    const int* __restrict__ basemat, const int* __restrict__ bucketbase,
    uint2* __restrict__ entries) {
    __shared__ int s[1024];
    __shared__ int wp[NB];       // running LDS write position per bucket
    __shared__ int gbase[NB];    // global dest = gbase[j] + local pos
    __shared__ uint2 sorted[CHUNK];
    __shared__ int dest[CHUNK];
    int t = threadIdx.x, b = blockIdx.x;

    // local exclusive scan of this block's 2048 bucket counts (2/thread)
    int c0 = histmat[b * NB + 2 * t];
    int c1 = histmat[b * NB + 2 * t + 1];
    int pair = c0 + c1;
    s[t] = pair;
    __syncthreads();
    for (int off = 1; off < 1024; off <<= 1) {
        int w = (t >= off) ? s[t - off] : 0;
        __syncthreads();
        s[t] += w;
        __syncthreads();
    }
    int excl = s[t] - pair;              // lofs of bucket 2t
    wp[2 * t] = excl;
    wp[2 * t + 1] = excl + c0;
    gbase[2 * t]     = bucketbase[2 * t]     + basemat[b * NB + 2 * t]     - excl;
    gbase[2 * t + 1] = bucketbase[2 * t + 1] + basemat[b * NB + 2 * t + 1] - (excl + c0);
    __syncthreads();

    int kbeg = b * CHUNK, kend = kbeg + CHUNK;
    for (int k = kbeg + t; k < kend; k += 1024) {
        unsigned r = (unsigned)row[k];
        unsigned j = r / RPB;
        unsigned rl = r - j * RPB;
        int pos = atomicAdd(&wp[j], 1);
        sorted[pos] = make_uint2((rl << 18) | (unsigned)col[k],
                                 __float_as_uint(vals[k]));
        dest[pos] = gbase[j] + pos;
    }
    __syncthreads();
    for (int i = t; i < CHUNK; i += 1024)
        entries[dest[i]] = sorted[i];
}

// P4: one block per bucket; stage in LDS, counting-sort by 74 local rows,
// rewrite region in place as fine CSR int2{col,val}; emit rowptr.
__global__ __launch_bounds__(512) void p4_sort(
    const int* __restrict__ bucketbase, uint2* __restrict__ entries,
    int* __restrict__ rowptr) {
    __shared__ uint2 stage[CAP];
    __shared__ int cnt[128], scanb[128], wp[128];
    int t = threadIdx.x, b = blockIdx.x;
    int base = bucketbase[b];
    int n = bucketbase[b + 1] - base;
    if (n > CAP) n = CAP;   // statistically impossible; avoids LDS overrun
    if (t < 128) cnt[t] = 0;
    __syncthreads();
    for (int i = t; i < n; i += 512) {
        uint2 e = entries[base + i];
        stage[i] = e;
        atomicAdd(&cnt[e.x >> 18], 1);
    }
    __syncthreads();
    if (t < 128) scanb[t] = cnt[t];
    __syncthreads();
    for (int off = 1; off < 128; off <<= 1) {
        int w = 0;
        if (t < 128 && t >= off) w = scanb[t - off];
        __syncthreads();
        if (t < 128) scanb[t] += w;
        __syncthreads();
    }
    if (t < RPB) {
        int excl = scanb[t] - cnt[t];
        wp[t] = excl;
        int rg = b * RPB + t;
        if (rg < N_TOTAL) rowptr[rg] = base + excl;
    }
    __syncthreads();
    for (int i = t; i < n; i += 512) {
        uint2 e = stage[i];
        unsigned rl = e.x >> 18;
        int pos = atomicAdd(&wp[rl], 1);
        ((int2*)entries)[base + pos] =
            make_int2((int)(e.x & 0x3FFFFu), (int)e.y);
    }
}

// 4 rows/wave, 16 lanes/row, bf16 gathers. y = S * x (bf16 out).
__global__ __launch_bounds__(256) void spmm_csr_kernel(
    const int* __restrict__ rowptr, const int2* __restrict__ csr,
    const ushort4* __restrict__ x4, ushort4* __restrict__ y4) {
    int gid = blockIdx.x * 256 + threadIdx.x;
    int lane = threadIdx.x & 63;
    int group = lane >> 4;
    int chunk = lane & 15;
    int r = (gid >> 6) * 4 + group;
    if (r >= N_TOTAL) return;
    int start = rowptr[r], end = rowptr[r + 1];
    float4 acc = make_float4(0.f, 0.f, 0.f, 0.f);
    for (int j0 = start; j0 < end; j0 += 16) {
        int j = j0 + chunk;
        int2 pair = make_int2(0, 0);
        if (j < end) pair = csr[j];
        int cnt = min(16, end - j0);
        #pragma unroll 4
        for (int t = 0; t < cnt; t++) {
            int src = group * 16 + t;
            int cc = __shfl(pair.x, src);
            float vv = __int_as_float(__shfl(pair.y, src));
            ushort4 xv = x4[cc * 16 + chunk];
            acc.x += vv * bf2f(xv.x);
            acc.y += vv * bf2f(xv.y);
            acc.z += vv * bf2f(xv.z);
            acc.w += vv * bf2f(xv.w);
        }
    }
    int o = r * 16 + chunk;
    ushort4 yb;
    yb.x = f2bf(acc.x); yb.y = f2bf(acc.y);
    yb.z = f2bf(acc.z); yb.w = f2bf(acc.w);
    y4[o] = yb;
}

// final layer fused with merge: acc = S*e2 (fp32 regs);
// out = (e0 + e1 + e2 + acc) * 0.25
__global__ __launch_bounds__(256) void spmm_merge_kernel(
    const int* __restrict__ rowptr, const int2* __restrict__ csr,
    const ushort4* __restrict__ x4 /*e2*/, const ushort4* __restrict__ e0,
    const ushort4* __restrict__ e1, float4* __restrict__ out) {
    int gid = blockIdx.x * 256 + threadIdx.x;
    int lane = threadIdx.x & 63;
    int group = lane >> 4;
    int chunk = lane & 15;
    int r = (gid >> 6) * 4 + group;
    if (r >= N_TOTAL) return;
    int start = rowptr[r], end = rowptr[r + 1];
    float4 acc = make_float4(0.f, 0.f, 0.f, 0.f);
    for (int j0 = start; j0 < end; j0 += 16) {
        int j = j0 + chunk;
        int2 pair = make_int2(0, 0);
        if (j < end) pair = csr[j];
        int cnt = min(16, end - j0);
        #pragma unroll 4
        for (int t = 0; t < cnt; t++) {
            int src = group * 16 + t;
            int cc = __shfl(pair.x, src);
            float vv = __int_as_float(__shfl(pair.y, src));
            ushort4 xv = x4[cc * 16 + chunk];
            acc.x += vv * bf2f(xv.x);
            acc.y += vv * bf2f(xv.y);
            acc.z += vv * bf2f(xv.z);
            acc.w += vv * bf2f(xv.w);
        }
    }
    int o = r * 16 + chunk;
    ushort4 a = e0[o], b = e1[o], c = x4[o];
    float4 oo;
    oo.x = (bf2f(a.x) + bf2f(b.x) + bf2f(c.x) + acc.x) * 0.25f;
    oo.y = (bf2f(a.y) + bf2f(b.y) + bf2f(c.y) + acc.y) * 0.25f;
    oo.z = (bf2f(a.z) + bf2f(b.z) + bf2f(c.z) + acc.z) * 0.25f;
    oo.w = (bf2f(a.w) + bf2f(b.w) + bf2f(c.w) + acc.w) * 0.25f;
    out[o] = oo;
}

extern "C" void kernel_launch(void* const* d_in, const int* in_sizes, int n_in,
                              void* d_out, int out_size, void* d_ws, size_t ws_size,
                              hipStream_t stream) {
    const float* user_emb = (const float*)d_in[0];
    const float* item_emb = (const float*)d_in[1];
    const int*   adj_row  = (const int*)d_in[2];
    const int*   adj_col  = (const int*)d_in[3];
    const float* adj_vals = (const float*)d_in[4];
    float* out = (float*)d_out;

    ush*   A          = (ush*)d_ws;                 // 19.2 MB (e0)
    ush*   B          = A + NELEM;                  // 19.2 MB (e1)
    ush*   C          = B + NELEM;                  // 19.2 MB (e2)
    uint2* entries    = (uint2*)(C + NELEM);        // 38.4 MB (becomes fine CSR)
    int*   histmat    = (int*)(entries + NNZ_C);    // 512*2048 = 4 MB
    int*   basemat    = histmat + NBLK * NB;        // 4 MB
    int*   tilesum    = basemat + NBLK * NB;        // 32*2048 = 256 KB
    int*   tilebase   = tilesum + TILES * NB;       // 256 KB
    int*   T          = tilebase + TILES * NB;      // 2048
    int*   bucketbase = T + NB;                     // 2049
    int*   rowptr     = bucketbase + NB + 1;        // 150001

    const int eltBlocks  = (NELEM4 + 255) / 256;
    const int spmmBlocks = N_TOTAL / 16;            // 9375 (exact)

    init_kernel<<<eltBlocks, 256, 0, stream>>>(
        (const float4*)user_emb, (const float4*)item_emb, (ushort4*)A);
    p1_hist<<<NBLK, 1024, 0, stream>>>(adj_row, histmat);
    p2a1_tilesum<<<dim3(NB / 256, TILES), 256, 0, stream>>>(histmat, tilesum);
    p2a2_tilescan<<<NB / 256, 256, 0, stream>>>(tilesum, tilebase, T);
    p2a3_expand<<<dim3(NB / 256, TILES), 256, 0, stream>>>(histmat, tilebase,
                                                           basemat);
    p2b_scan<<<1, 1024, 0, stream>>>(T, bucketbase, rowptr);
    p3_scatter<<<NBLK, 1024, 0, stream>>>(adj_row, adj_col, adj_vals,
                                          histmat, basemat, bucketbase, entries);
    p4_sort<<<NB, 512, 0, stream>>>(bucketbase, entries, rowptr);

    spmm_csr_kernel<<<spmmBlocks, 256, 0, stream>>>(rowptr, (const int2*)entries,
        (const ushort4*)A, (ushort4*)B);    // e1 = S e0
    spmm_csr_kernel<<<spmmBlocks, 256, 0, stream>>>(rowptr, (const int2*)entries,
        (const ushort4*)B, (ushort4*)C);    // e2 = S e1
    spmm_merge_kernel<<<spmmBlocks, 256, 0, stream>>>(rowptr, (const int2*)entries,
        (const ushort4*)C, (const ushort4*)A, (const ushort4*)B, (float4*)out);
}